// Round 4
// baseline (302.864 us; speedup 1.0000x reference)
//
#include <hip/hip_runtime.h>

// ---------------- kernels ----------------

__global__ void k_zero(float* __restrict__ deg, int* __restrict__ cnt, int NPAD) {
    int n = blockIdx.x * blockDim.x + threadIdx.x;
    if (n < NPAD) { deg[n] = 0.0f; cnt[n] = 0; }
}

// histogram: weighted degree (float) + edge count (int); compact ew cache
__global__ void k_hist(const int* __restrict__ ei, const float* __restrict__ ea,
                       float* __restrict__ ewc, float* __restrict__ deg,
                       int* __restrict__ cnt, int E) {
    int e = blockIdx.x * blockDim.x + threadIdx.x;
    if (e >= E) return;
    int d = ei[E + e];
    float w = ea[(size_t)e * 16 + 15];
    ewc[e] = w;
    atomicAdd(deg + d, w);
    atomicAdd(cnt + d, 1);
}

// block-wise inclusive scan of counts (1024/block) + fused dinv
__global__ void k_scan1(const int* __restrict__ cnt, int* __restrict__ incl,
                        int* __restrict__ parts, const float* __restrict__ deg,
                        float* __restrict__ dinv, int N) {
    __shared__ int s[1024];
    int tid = threadIdx.x;
    int n = blockIdx.x * 1024 + tid;
    s[tid] = (n < N) ? cnt[n] : 0;
    if (n < N) dinv[n] = 1.0f / sqrtf(deg[n] + 1.0f);
    __syncthreads();
    for (int off = 1; off < 1024; off <<= 1) {
        int t = (tid >= off) ? s[tid - off] : 0;
        __syncthreads();
        s[tid] += t;
        __syncthreads();
    }
    incl[n] = s[tid];
    if (tid == 1023) parts[blockIdx.x] = s[1023];
}

// fused: each block computes its own exclusive block-offset from parts (nb<=64)
// then finalizes rs/cur. 1024 threads/block, nb blocks.
__global__ void k_scan23(const int* __restrict__ incl, const int* __restrict__ cnt,
                         const int* __restrict__ parts, int* __restrict__ rs,
                         int* __restrict__ cur, int N, int nb) {
    __shared__ int soff;
    int tid = threadIdx.x;
    if (tid < 64) {
        int v = (tid < nb && tid < (int)blockIdx.x) ? parts[tid] : 0;
        #pragma unroll
        for (int off = 32; off >= 1; off >>= 1) v += __shfl_down(v, off);
        if (tid == 0) soff = v;
    }
    __syncthreads();
    int n = blockIdx.x * 1024 + tid;
    if (n < N) {
        int v = incl[n] - cnt[n] + soff;
        rs[n] = v; cur[n] = v;
    }
}

// Fat kernel: blocks [0, scatterBlocks) bucket edges by dst (CSR build);
// remaining blocks do mean(x) @ W1 with fully-coalesced x reads.
__global__ __launch_bounds__(256) void k_scattermean(
        const int* __restrict__ ei, const float* __restrict__ ewc,
        const float* __restrict__ dinv, int* __restrict__ cur,
        int2* __restrict__ eb, int E, int scatterBlocks,
        const float* __restrict__ x, const float* __restrict__ W1,
        float* __restrict__ h1, int N) {
    int tid = threadIdx.x;
    if ((int)blockIdx.x < scatterBlocks) {
        int e = blockIdx.x * 256 + tid;
        if (e < E) {
            int s = ei[e];
            int d = ei[E + e];
            float nm = dinv[s] * ewc[e] * dinv[d];
            int p = atomicAdd(cur + d, 1);
            eb[p] = make_int2(s, __float_as_int(nm));
        }
        return;
    }
    __shared__ float Wl[4096];
    {
        const float4* W4 = (const float4*)W1;
        float4* Wl4 = (float4*)Wl;
        #pragma unroll
        for (int i = 0; i < 4; ++i) Wl4[i * 256 + tid] = W4[i * 256 + tid];
    }
    __syncthreads();
    int bid = (int)blockIdx.x - scatterBlocks;
    int w = tid >> 6, l = tid & 63;
    for (int it = 0; it < 4; ++it) {
        int n = bid * 16 + it * 4 + w;          // wave-uniform
        if (n >= N) continue;
        // coalesced: instruction k reads float4 #(k*64+l) of the node's 1024 floats.
        // float4 (k*64+l) covers flat floats f=(k*64+l)*4.. +3, all inside channel
        // c = k*16 + (l>>2) (t = (l&3)*4 .. +3).
        const float4* xp = (const float4*)(x + (size_t)n * 1024);
        float4 v0 = xp[l], v1 = xp[64 + l], v2 = xp[128 + l], v3 = xp[192 + l];
        float s0 = (v0.x + v0.y) + (v0.z + v0.w);
        float s1 = (v1.x + v1.y) + (v1.z + v1.w);
        float s2 = (v2.x + v2.y) + (v2.z + v2.w);
        float s3 = (v3.x + v3.y) + (v3.z + v3.w);
        // quad reduction: every lane in a 4-lane group gets the channel total
        s0 += __shfl_xor(s0, 1); s0 += __shfl_xor(s0, 2);
        s1 += __shfl_xor(s1, 1); s1 += __shfl_xor(s1, 2);
        s2 += __shfl_xor(s2, 1); s2 += __shfl_xor(s2, 2);
        s3 += __shfl_xor(s3, 1); s3 += __shfl_xor(s3, 2);
        float xa0 = s0 * 0.0625f, xa1 = s1 * 0.0625f;
        float xa2 = s2 * 0.0625f, xa3 = s3 * 0.0625f;
        // lane l now holds xa[c] for c = k*16 + (l>>2); broadcast via shfl(lane j*4)
        float acc = 0.0f;
        #pragma unroll
        for (int j = 0; j < 16; ++j) {
            float r0 = __shfl(xa0, j * 4);
            float r1 = __shfl(xa1, j * 4);
            float r2 = __shfl(xa2, j * 4);
            float r3 = __shfl(xa3, j * 4);
            acc = fmaf(r0, Wl[(j     ) * 64 + l], acc);
            acc = fmaf(r1, Wl[(16 + j) * 64 + l], acc);
            acc = fmaf(r2, Wl[(32 + j) * 64 + l], acc);
            acc = fmaf(r3, Wl[(48 + j) * 64 + l], acc);
        }
        h1[(size_t)n * 64 + l] = acc;
    }
}

// Fused GCN aggregation + row GEMM. One wave per node, lane = channel.
// 8 outstanding gathers to cover L2/L3 latency.
template <int RELU, int HAS_BOUT>
__global__ __launch_bounds__(256) void k_aggW(const float* __restrict__ in,
                                              const float* __restrict__ bias,
                                              const float* __restrict__ Wm,
                                              const float* __restrict__ bout,
                                              const float* __restrict__ dinv,
                                              const int* __restrict__ rs,
                                              const int* __restrict__ cnt,
                                              const int2* __restrict__ eb,
                                              float* __restrict__ out, int N) {
    __shared__ float Wl[4096];
    int tid = threadIdx.x;
    {
        const float4* W4 = (const float4*)Wm;
        float4* Wl4 = (float4*)Wl;
        #pragma unroll
        for (int i = 0; i < 4; ++i) Wl4[i * 256 + tid] = W4[i * 256 + tid];
    }
    __syncthreads();
    int w = tid >> 6, c = tid & 63;
    for (int it = 0; it < 4; ++it) {
        int n = blockIdx.x * 16 + it * 4 + w;   // wave-uniform
        if (n >= N) continue;
        float dv = dinv[n];
        float a0 = fmaf(in[(size_t)n * 64 + c] * dv, dv, bias[c]);
        float a1 = 0.f, a2 = 0.f, a3 = 0.f;
        int st = rs[n], m = cnt[n];
        int i = 0;
        for (; i + 8 <= m; i += 8) {
            int2 e0 = eb[st + i + 0], e1 = eb[st + i + 1];
            int2 e2 = eb[st + i + 2], e3 = eb[st + i + 3];
            int2 e4 = eb[st + i + 4], e5 = eb[st + i + 5];
            int2 e6 = eb[st + i + 6], e7 = eb[st + i + 7];
            float v0 = in[(size_t)e0.x * 64 + c], v1 = in[(size_t)e1.x * 64 + c];
            float v2 = in[(size_t)e2.x * 64 + c], v3 = in[(size_t)e3.x * 64 + c];
            float v4 = in[(size_t)e4.x * 64 + c], v5 = in[(size_t)e5.x * 64 + c];
            float v6 = in[(size_t)e6.x * 64 + c], v7 = in[(size_t)e7.x * 64 + c];
            a0 = fmaf(v0, __int_as_float(e0.y), a0);
            a1 = fmaf(v1, __int_as_float(e1.y), a1);
            a2 = fmaf(v2, __int_as_float(e2.y), a2);
            a3 = fmaf(v3, __int_as_float(e3.y), a3);
            a0 = fmaf(v4, __int_as_float(e4.y), a0);
            a1 = fmaf(v5, __int_as_float(e5.y), a1);
            a2 = fmaf(v6, __int_as_float(e6.y), a2);
            a3 = fmaf(v7, __int_as_float(e7.y), a3);
        }
        for (; i + 4 <= m; i += 4) {
            int2 e0 = eb[st + i], e1 = eb[st + i + 1], e2 = eb[st + i + 2], e3 = eb[st + i + 3];
            float v0 = in[(size_t)e0.x * 64 + c], v1 = in[(size_t)e1.x * 64 + c];
            float v2 = in[(size_t)e2.x * 64 + c], v3 = in[(size_t)e3.x * 64 + c];
            a0 = fmaf(v0, __int_as_float(e0.y), a0);
            a1 = fmaf(v1, __int_as_float(e1.y), a1);
            a2 = fmaf(v2, __int_as_float(e2.y), a2);
            a3 = fmaf(v3, __int_as_float(e3.y), a3);
        }
        for (; i < m; ++i) {
            int2 e = eb[st + i];
            a0 = fmaf(in[(size_t)e.x * 64 + c], __int_as_float(e.y), a0);
        }
        float r = (a0 + a1) + (a2 + a3);
        if (RELU) r = fmaxf(r, 0.0f);
        float acc = HAS_BOUT ? bout[c] : 0.0f;
        #pragma unroll
        for (int cc = 0; cc < 64; ++cc) {
            float rv = __shfl(r, cc);
            acc = fmaf(rv, Wl[cc * 64 + c], acc);
        }
        out[(size_t)n * 64 + c] = acc;
    }
}

// ---------------- launcher ----------------

extern "C" void kernel_launch(void* const* d_in, const int* in_sizes, int n_in,
                              void* d_out, int out_size, void* d_ws, size_t ws_size,
                              hipStream_t stream) {
    const float* x    = (const float*)d_in[0];
    const int*   ei   = (const int*)d_in[1];
    const float* ea   = (const float*)d_in[2];
    const float* W1   = (const float*)d_in[3];
    const float* b1   = (const float*)d_in[4];
    const float* W2   = (const float*)d_in[5];
    const float* b2   = (const float*)d_in[6];
    const float* Wout = (const float*)d_in[7];
    const float* bout = (const float*)d_in[8];
    float* out = (float*)d_out;

    const int N = in_sizes[0] / (64 * 16);   // 50000
    const int E = in_sizes[1] / 2;           // 800000
    const int nb = (N + 1023) / 1024;        // 49
    const int NPAD = nb * 1024;

    float* ws = (float*)d_ws;
    size_t NC = (size_t)N * 64;
    float* H1   = ws;                 // h1 = xa@W1 ; gather source of layer 1
    float* H2   = ws + NC;            // relu(conv1)@W2 ; gather source of layer 2
    float* deg  = ws + 2 * NC;
    int*   cnt  = (int*)(deg + NPAD);
    float* dinv = (float*)(cnt + NPAD);
    int*   rs   = (int*)(dinv + NPAD);
    int*   cur  = rs + NPAD;
    int*   incl = cur + NPAD;
    int*   parts= incl + NPAD;
    float* ewc  = (float*)(parts + 256);
    int2*  eb   = (int2*)(ewc + E);   // even float offset -> 8B aligned

    dim3 b256(256);
    int meanBlocks    = (N + 15) / 16;       // 3125
    int scatterBlocks = (E + 255) / 256;     // 3125
    hipLaunchKernelGGL(k_zero,   dim3((2 * NPAD + 255) / 256), b256, 0, stream, deg, cnt, 2 * NPAD);
    hipLaunchKernelGGL(k_hist,   dim3((E + 255) / 256), b256, 0, stream, ei, ea, ewc, deg, cnt, E);
    hipLaunchKernelGGL(k_scan1,  dim3(nb), dim3(1024), 0, stream, cnt, incl, parts, deg, dinv, N);
    hipLaunchKernelGGL(k_scan23, dim3(nb), dim3(1024), 0, stream, incl, cnt, parts, rs, cur, N, nb);
    hipLaunchKernelGGL(k_scattermean, dim3(scatterBlocks + meanBlocks), b256, 0, stream,
                       ei, ewc, dinv, cur, eb, E, scatterBlocks, x, W1, H1, N);

    // layer 1 conv (+b1, relu) fused with @W2  -> H2
    hipLaunchKernelGGL((k_aggW<1, 0>), dim3(meanBlocks), b256, 0, stream,
                       H1, b1, W2, (const float*)nullptr, dinv, rs, cnt, eb, H2, N);
    // layer 2 conv (+b2) fused with @Wout + bout -> out
    hipLaunchKernelGGL((k_aggW<0, 1>), dim3(meanBlocks), b256, 0, stream,
                       H2, b2, Wout, bout, dinv, rs, cnt, eb, out, N);
}

// Round 5
// 249.897 us; speedup vs baseline: 1.2120x; 1.2120x over previous
//
#include <hip/hip_runtime.h>

#define CAP 64
#define OVF_MAX 8192

// ---------------- kernels ----------------

__global__ void k_zero(int* __restrict__ cur, int* __restrict__ ovf_cnt, int N) {
    int n = blockIdx.x * blockDim.x + threadIdx.x;
    if (n < N) cur[n] = 0;
    if (n == N) *ovf_cnt = 0;
}

// Fat kernel:
//  blocks [0, scatterBlocks): bucket edges by dst (one atomic per edge)
//  blocks [scatterBlocks, ..): mean over T of x, then @W1 -> h1 (coalesced x reads)
__global__ __launch_bounds__(256) void k_scatmean(
        const int* __restrict__ ei, const float* __restrict__ ea,
        int* __restrict__ cur, int2* __restrict__ eb,
        int* __restrict__ ovf_cnt, int4* __restrict__ ovf,
        int E, int scatterBlocks,
        const float* __restrict__ x, const float* __restrict__ W1,
        float* __restrict__ h1, int N) {
    int tid = threadIdx.x;
    if ((int)blockIdx.x < scatterBlocks) {
        int e = blockIdx.x * 256 + tid;
        if (e < E) {
            int s = ei[e];
            int d = ei[E + e];
            float w = ea[(size_t)e * 16 + 15];
            int p = atomicAdd(cur + d, 1);
            if (p < CAP) {
                eb[(size_t)d * CAP + p] = make_int2(s, __float_as_int(w));
            } else {
                int q = atomicAdd(ovf_cnt, 1);
                if (q < OVF_MAX) ovf[q] = make_int4(s, d, __float_as_int(w), 0);
            }
        }
        return;
    }
    __shared__ float Wl[4096];
    {
        const float4* W4 = (const float4*)W1;
        float4* Wl4 = (float4*)Wl;
        #pragma unroll
        for (int i = 0; i < 4; ++i) Wl4[i * 256 + tid] = W4[i * 256 + tid];
    }
    __syncthreads();
    int bid = (int)blockIdx.x - scatterBlocks;
    int w = tid >> 6, l = tid & 63;
    for (int it = 0; it < 4; ++it) {
        int n = bid * 16 + it * 4 + w;          // wave-uniform
        if (n >= N) continue;
        // instruction k reads float4 #(k*64+l): fully coalesced 1KB per instr.
        // float4 (k*64+l) lies inside channel c = k*16 + (l>>2).
        const float4* xp = (const float4*)(x + (size_t)n * 1024);
        float4 v0 = xp[l], v1 = xp[64 + l], v2 = xp[128 + l], v3 = xp[192 + l];
        float s0 = (v0.x + v0.y) + (v0.z + v0.w);
        float s1 = (v1.x + v1.y) + (v1.z + v1.w);
        float s2 = (v2.x + v2.y) + (v2.z + v2.w);
        float s3 = (v3.x + v3.y) + (v3.z + v3.w);
        s0 += __shfl_xor(s0, 1); s0 += __shfl_xor(s0, 2);
        s1 += __shfl_xor(s1, 1); s1 += __shfl_xor(s1, 2);
        s2 += __shfl_xor(s2, 1); s2 += __shfl_xor(s2, 2);
        s3 += __shfl_xor(s3, 1); s3 += __shfl_xor(s3, 2);
        float xa0 = s0 * 0.0625f, xa1 = s1 * 0.0625f;
        float xa2 = s2 * 0.0625f, xa3 = s3 * 0.0625f;
        float acc = 0.0f;
        #pragma unroll
        for (int j = 0; j < 16; ++j) {
            float r0 = __shfl(xa0, j * 4);
            float r1 = __shfl(xa1, j * 4);
            float r2 = __shfl(xa2, j * 4);
            float r3 = __shfl(xa3, j * 4);
            acc = fmaf(r0, Wl[(j     ) * 64 + l], acc);
            acc = fmaf(r1, Wl[(16 + j) * 64 + l], acc);
            acc = fmaf(r2, Wl[(32 + j) * 64 + l], acc);
            acc = fmaf(r3, Wl[(48 + j) * 64 + l], acc);
        }
        h1[(size_t)n * 64 + l] = acc;
    }
}

// dinv[n] = 1/sqrt(1 + sum of ew over node n's bucket). 4 lanes per node.
__global__ void k_dinvb(const int* __restrict__ cur, const int2* __restrict__ eb,
                        const int* __restrict__ ovf_cnt, const int4* __restrict__ ovf,
                        float* __restrict__ dinv, int N) {
    int tid = threadIdx.x;
    int n = blockIdx.x * 64 + (tid >> 2);
    int j = tid & 3;
    if (n >= N) return;
    int mfull = cur[n];
    int m = mfull > CAP ? CAP : mfull;
    float s = 0.0f;
    for (int i = j; i < m; i += 4) s += __int_as_float(eb[(size_t)n * CAP + i].y);
    s += __shfl_xor(s, 1);
    s += __shfl_xor(s, 2);
    if (j == 0) {
        if (mfull > CAP) {
            int oc = *ovf_cnt; if (oc > OVF_MAX) oc = OVF_MAX;
            for (int k = 0; k < oc; ++k) {
                int4 o = ovf[k];
                if (o.y == n) s += __int_as_float(o.z);
            }
        }
        dinv[n] = 1.0f / sqrtf(s + 1.0f);
    }
}

// Fused GCN aggregation + row GEMM. One wave per node, lane = channel.
// sum = Σ_e in[src][c] * (ew*dinv[src]);  r = dv*(sum + in[n][c]*dv) + bias[c]
// out[n][c] = Σ_cc r[cc]*Wm[cc][c] (+bout)
template <int RELU, int HAS_BOUT>
__global__ __launch_bounds__(256) void k_aggW(const float* __restrict__ in,
                                              const float* __restrict__ bias,
                                              const float* __restrict__ Wm,
                                              const float* __restrict__ bout,
                                              const float* __restrict__ dinv,
                                              const int* __restrict__ cur,
                                              const int2* __restrict__ eb,
                                              const int* __restrict__ ovf_cnt,
                                              const int4* __restrict__ ovf,
                                              float* __restrict__ out, int N) {
    __shared__ float Wl[4096];
    int tid = threadIdx.x;
    {
        const float4* W4 = (const float4*)Wm;
        float4* Wl4 = (float4*)Wl;
        #pragma unroll
        for (int i = 0; i < 4; ++i) Wl4[i * 256 + tid] = W4[i * 256 + tid];
    }
    __syncthreads();
    int w = tid >> 6, c = tid & 63;
    for (int it = 0; it < 4; ++it) {
        int n = blockIdx.x * 16 + it * 4 + w;   // wave-uniform
        if (n >= N) continue;
        float dv = dinv[n];
        float selfv = in[(size_t)n * 64 + c];
        float a0 = 0.f, a1 = 0.f, a2 = 0.f, a3 = 0.f;
        const int2* bkt = eb + (size_t)n * CAP;
        int mfull = cur[n];
        int m = mfull > CAP ? CAP : mfull;
        int i = 0;
        for (; i + 8 <= m; i += 8) {
            int2 e0 = bkt[i + 0], e1 = bkt[i + 1], e2 = bkt[i + 2], e3 = bkt[i + 3];
            int2 e4 = bkt[i + 4], e5 = bkt[i + 5], e6 = bkt[i + 6], e7 = bkt[i + 7];
            float d0 = dinv[e0.x], d1 = dinv[e1.x], d2 = dinv[e2.x], d3 = dinv[e3.x];
            float d4 = dinv[e4.x], d5 = dinv[e5.x], d6 = dinv[e6.x], d7 = dinv[e7.x];
            float v0 = in[(size_t)e0.x * 64 + c], v1 = in[(size_t)e1.x * 64 + c];
            float v2 = in[(size_t)e2.x * 64 + c], v3 = in[(size_t)e3.x * 64 + c];
            float v4 = in[(size_t)e4.x * 64 + c], v5 = in[(size_t)e5.x * 64 + c];
            float v6 = in[(size_t)e6.x * 64 + c], v7 = in[(size_t)e7.x * 64 + c];
            a0 = fmaf(v0, __int_as_float(e0.y) * d0, a0);
            a1 = fmaf(v1, __int_as_float(e1.y) * d1, a1);
            a2 = fmaf(v2, __int_as_float(e2.y) * d2, a2);
            a3 = fmaf(v3, __int_as_float(e3.y) * d3, a3);
            a0 = fmaf(v4, __int_as_float(e4.y) * d4, a0);
            a1 = fmaf(v5, __int_as_float(e5.y) * d5, a1);
            a2 = fmaf(v6, __int_as_float(e6.y) * d6, a2);
            a3 = fmaf(v7, __int_as_float(e7.y) * d7, a3);
        }
        for (; i < m; ++i) {
            int2 e = bkt[i];
            a0 = fmaf(in[(size_t)e.x * 64 + c], __int_as_float(e.y) * dinv[e.x], a0);
        }
        if (mfull > CAP) {           // wave-uniform, ~never taken
            int oc = *ovf_cnt; if (oc > OVF_MAX) oc = OVF_MAX;
            for (int k = 0; k < oc; ++k) {
                int4 o = ovf[k];
                if (o.y == n)
                    a0 = fmaf(in[(size_t)o.x * 64 + c], __int_as_float(o.z) * dinv[o.x], a0);
            }
        }
        float r = fmaf(dv, ((a0 + a1) + (a2 + a3)) + selfv * dv, bias[c]);
        if (RELU) r = fmaxf(r, 0.0f);
        float acc = HAS_BOUT ? bout[c] : 0.0f;
        #pragma unroll
        for (int cc = 0; cc < 64; ++cc) {
            float rv = __shfl(r, cc);
            acc = fmaf(rv, Wl[cc * 64 + c], acc);
        }
        out[(size_t)n * 64 + c] = acc;
    }
}

// ---------------- launcher ----------------

extern "C" void kernel_launch(void* const* d_in, const int* in_sizes, int n_in,
                              void* d_out, int out_size, void* d_ws, size_t ws_size,
                              hipStream_t stream) {
    const float* x    = (const float*)d_in[0];
    const int*   ei   = (const int*)d_in[1];
    const float* ea   = (const float*)d_in[2];
    const float* W1   = (const float*)d_in[3];
    const float* b1   = (const float*)d_in[4];
    const float* W2   = (const float*)d_in[5];
    const float* b2   = (const float*)d_in[6];
    const float* Wout = (const float*)d_in[7];
    const float* bout = (const float*)d_in[8];
    float* out = (float*)d_out;

    const int N = in_sizes[0] / (64 * 16);   // 50000
    const int E = in_sizes[1] / 2;           // 800000

    // workspace layout (floats/ints, 16B-aligned chunks)
    char* wsb = (char*)d_ws;
    int4*  ovf  = (int4*)wsb;                       // OVF_MAX * 16B = 128KB
    int2*  eb   = (int2*)(wsb + OVF_MAX * 16);      // N*CAP*8B = 25.6MB
    float* H1   = (float*)(wsb + OVF_MAX * 16 + (size_t)N * CAP * 8);
    size_t NC = (size_t)N * 64;
    float* H2   = H1 + NC;
    int*   cur  = (int*)(H2 + NC);
    float* dinv = (float*)(cur + N);
    int*   ovfc = (int*)(dinv + N);

    dim3 b256(256);
    int meanBlocks    = (N + 15) / 16;       // 3125
    int scatterBlocks = (E + 255) / 256;     // 3125
    hipLaunchKernelGGL(k_zero, dim3((N + 256) / 256 + 1), b256, 0, stream, cur, ovfc, N);
    hipLaunchKernelGGL(k_scatmean, dim3(scatterBlocks + meanBlocks), b256, 0, stream,
                       ei, ea, cur, eb, ovfc, ovf, E, scatterBlocks, x, W1, H1, N);
    hipLaunchKernelGGL(k_dinvb, dim3((N + 63) / 64), b256, 0, stream, cur, eb, ovfc, ovf, dinv, N);

    // layer 1 conv (+b1, relu) fused with @W2  -> H2
    hipLaunchKernelGGL((k_aggW<1, 0>), dim3(meanBlocks), b256, 0, stream,
                       H1, b1, W2, (const float*)nullptr, dinv, cur, eb, ovfc, ovf, H2, N);
    // layer 2 conv (+b2) fused with @Wout + bout -> out
    hipLaunchKernelGGL((k_aggW<0, 1>), dim3(meanBlocks), b256, 0, stream,
                       H2, b2, Wout, bout, dinv, cur, eb, ovfc, ovf, out, N);
}

// Round 6
// 202.612 us; speedup vs baseline: 1.4948x; 1.2334x over previous
//
#include <hip/hip_runtime.h>

#define CAP 64
#define OVF_MAX 8192
#define WPAD 68

// ---------------- kernels ----------------

// Fat prelude: zero cur/ovfc; 16 blocks compute WcT = (W2@Wout)^T; 1 block bc.
__global__ void k_pre(int* __restrict__ cur, int* __restrict__ ovfc, int N,
                      const float* __restrict__ W2, const float* __restrict__ Wout,
                      const float* __restrict__ b2, const float* __restrict__ bout,
                      float* __restrict__ WcT, float* __restrict__ bc, int zb) {
    int tid = threadIdx.x;
    int bid = blockIdx.x;
    if (bid < zb) {
        int n = bid * 256 + tid;
        if (n < N) cur[n] = 0;
        if (n == N) *ovfc = 0;
        return;
    }
    int wb = bid - zb;
    if (wb < 16) {
        int idx = wb * 256 + tid;
        int j = idx >> 6, i = idx & 63;
        float s = 0.0f;
        #pragma unroll 8
        for (int m = 0; m < 64; ++m)
            s = fmaf(W2[i * 64 + m], Wout[m * 64 + j], s);
        WcT[idx] = s;                       // WcT[j*64 + i] = Wc[i][j]
    } else if (tid < 64) {
        float s = bout[tid];
        for (int k = 0; k < 64; ++k)
            s = fmaf(b2[k], Wout[k * 64 + tid], s);
        bc[tid] = s;
    }
}

// Fat kernel:
//  blocks [0, scatterBlocks): bucket edges by dst (one atomic per edge)
//  blocks [scatterBlocks, ..): mean over T of x, then @W1 -> h1 (LDS-staged GEMM)
__global__ __launch_bounds__(256) void k_scatmean(
        const int* __restrict__ ei, const float* __restrict__ ea,
        int* __restrict__ cur, int2* __restrict__ eb,
        int* __restrict__ ovf_cnt, int4* __restrict__ ovf,
        int E, int scatterBlocks,
        const float* __restrict__ x, const float* __restrict__ W1,
        float* __restrict__ h1, int N) {
    int tid = threadIdx.x;
    if ((int)blockIdx.x < scatterBlocks) {
        int e = blockIdx.x * 256 + tid;
        if (e < E) {
            int s = ei[e];
            int d = ei[E + e];
            float w = ea[(size_t)e * 16 + 15];
            int p = atomicAdd(cur + d, 1);
            if (p < CAP) {
                eb[(size_t)d * CAP + p] = make_int2(s, __float_as_int(w));
            } else {
                int q = atomicAdd(ovf_cnt, 1);
                if (q < OVF_MAX) ovf[q] = make_int4(s, d, __float_as_int(w), 0);
            }
        }
        return;
    }
    __shared__ float Wt[64 * WPAD];          // W1^T, padded rows
    __shared__ float rbuf[4 * 64];           // per-wave r staging
    {
        const float4* W4 = (const float4*)W1;
        #pragma unroll
        for (int i = 0; i < 4; ++i) {
            int f4 = i * 256 + tid;
            float4 v = W4[f4];
            int cc = f4 >> 4;                 // row of W1
            int l0 = (f4 & 15) * 4;           // col of W1
            Wt[(l0 + 0) * WPAD + cc] = v.x;
            Wt[(l0 + 1) * WPAD + cc] = v.y;
            Wt[(l0 + 2) * WPAD + cc] = v.z;
            Wt[(l0 + 3) * WPAD + cc] = v.w;
        }
    }
    __syncthreads();
    int bid = (int)blockIdx.x - scatterBlocks;
    int w = tid >> 6, l = tid & 63;
    float* rw = rbuf + w * 64;
    for (int it = 0; it < 4; ++it) {
        int n = bid * 16 + it * 4 + w;        // wave-uniform
        if (n >= N) continue;
        // coalesced 1KB reads; float4 #(k*64+l) lies in channel c = k*16 + (l>>2)
        const float4* xp = (const float4*)(x + (size_t)n * 1024);
        float4 v0 = xp[l], v1 = xp[64 + l], v2 = xp[128 + l], v3 = xp[192 + l];
        float s0 = (v0.x + v0.y) + (v0.z + v0.w);
        float s1 = (v1.x + v1.y) + (v1.z + v1.w);
        float s2 = (v2.x + v2.y) + (v2.z + v2.w);
        float s3 = (v3.x + v3.y) + (v3.z + v3.w);
        s0 += __shfl_xor(s0, 1); s0 += __shfl_xor(s0, 2);
        s1 += __shfl_xor(s1, 1); s1 += __shfl_xor(s1, 2);
        s2 += __shfl_xor(s2, 1); s2 += __shfl_xor(s2, 2);
        s3 += __shfl_xor(s3, 1); s3 += __shfl_xor(s3, 2);
        if ((l & 3) == 0) {                   // quad leader writes its 4 channels
            int q = l >> 2;
            rw[q]      = s0 * 0.0625f;
            rw[q + 16] = s1 * 0.0625f;
            rw[q + 32] = s2 * 0.0625f;
            rw[q + 48] = s3 * 0.0625f;
        }
        // wave-internal DS ordering: compiler inserts lgkmcnt before reads
        float acc = 0.0f;
        const float4* rb4 = (const float4*)rw;
        const float4* wt4 = (const float4*)(Wt + l * WPAD);
        #pragma unroll
        for (int q = 0; q < 16; ++q) {
            float4 rv = rb4[q];               // broadcast (same addr all lanes)
            float4 wv = wt4[q];
            acc = fmaf(rv.x, wv.x, acc);
            acc = fmaf(rv.y, wv.y, acc);
            acc = fmaf(rv.z, wv.z, acc);
            acc = fmaf(rv.w, wv.w, acc);
        }
        h1[(size_t)n * 64 + l] = acc;
    }
}

// dinv[n] = 1/sqrt(1 + sum of ew over node n's bucket). 4 lanes per node.
__global__ void k_dinvb(const int* __restrict__ cur, const int2* __restrict__ eb,
                        const int* __restrict__ ovf_cnt, const int4* __restrict__ ovf,
                        float* __restrict__ dinv, int N) {
    int tid = threadIdx.x;
    int n = blockIdx.x * 64 + (tid >> 2);
    int j = tid & 3;
    if (n >= N) return;
    int mfull = cur[n];
    int m = mfull > CAP ? CAP : mfull;
    float s = 0.0f;
    for (int i = j; i < m; i += 4) s += __int_as_float(eb[(size_t)n * CAP + i].y);
    s += __shfl_xor(s, 1);
    s += __shfl_xor(s, 2);
    if (j == 0) {
        if (mfull > CAP) {
            int oc = *ovf_cnt; if (oc > OVF_MAX) oc = OVF_MAX;
            for (int k = 0; k < oc; ++k) {
                int4 o = ovf[k];
                if (o.y == n) s += __int_as_float(o.z);
            }
        }
        dinv[n] = 1.0f / sqrtf(s + 1.0f);
    }
}

// Layer-1: pure gather + bias + relu (GEMM folded out). One wave per node.
__global__ __launch_bounds__(256) void k_agg1(const float* __restrict__ in,
                                              const float* __restrict__ bias,
                                              const float* __restrict__ dinv,
                                              const int* __restrict__ cur,
                                              const int2* __restrict__ eb,
                                              const int* __restrict__ ovf_cnt,
                                              const int4* __restrict__ ovf,
                                              float* __restrict__ out, int N) {
    int tid = threadIdx.x;
    int w = tid >> 6, c = tid & 63;
    for (int it = 0; it < 4; ++it) {
        int n = blockIdx.x * 16 + it * 4 + w;
        if (n >= N) continue;
        float dv = dinv[n];
        float selfv = in[(size_t)n * 64 + c];
        float a0 = 0.f, a1 = 0.f, a2 = 0.f, a3 = 0.f;
        const int2* bkt = eb + (size_t)n * CAP;
        int mfull = cur[n];
        int m = mfull > CAP ? CAP : mfull;
        int i = 0;
        for (; i + 8 <= m; i += 8) {
            int2 e0 = bkt[i + 0], e1 = bkt[i + 1], e2 = bkt[i + 2], e3 = bkt[i + 3];
            int2 e4 = bkt[i + 4], e5 = bkt[i + 5], e6 = bkt[i + 6], e7 = bkt[i + 7];
            float d0 = dinv[e0.x], d1 = dinv[e1.x], d2 = dinv[e2.x], d3 = dinv[e3.x];
            float d4 = dinv[e4.x], d5 = dinv[e5.x], d6 = dinv[e6.x], d7 = dinv[e7.x];
            float v0 = in[(size_t)e0.x * 64 + c], v1 = in[(size_t)e1.x * 64 + c];
            float v2 = in[(size_t)e2.x * 64 + c], v3 = in[(size_t)e3.x * 64 + c];
            float v4 = in[(size_t)e4.x * 64 + c], v5 = in[(size_t)e5.x * 64 + c];
            float v6 = in[(size_t)e6.x * 64 + c], v7 = in[(size_t)e7.x * 64 + c];
            a0 = fmaf(v0, __int_as_float(e0.y) * d0, a0);
            a1 = fmaf(v1, __int_as_float(e1.y) * d1, a1);
            a2 = fmaf(v2, __int_as_float(e2.y) * d2, a2);
            a3 = fmaf(v3, __int_as_float(e3.y) * d3, a3);
            a0 = fmaf(v4, __int_as_float(e4.y) * d4, a0);
            a1 = fmaf(v5, __int_as_float(e5.y) * d5, a1);
            a2 = fmaf(v6, __int_as_float(e6.y) * d6, a2);
            a3 = fmaf(v7, __int_as_float(e7.y) * d7, a3);
        }
        for (; i < m; ++i) {
            int2 e = bkt[i];
            a0 = fmaf(in[(size_t)e.x * 64 + c], __int_as_float(e.y) * dinv[e.x], a0);
        }
        if (mfull > CAP) {
            int oc = *ovf_cnt; if (oc > OVF_MAX) oc = OVF_MAX;
            for (int k = 0; k < oc; ++k) {
                int4 o = ovf[k];
                if (o.y == n)
                    a0 = fmaf(in[(size_t)o.x * 64 + c], __int_as_float(o.z) * dinv[o.x], a0);
            }
        }
        float r = fmaf(dv, ((a0 + a1) + (a2 + a3)) + selfv * dv, bias[c]);
        out[(size_t)n * 64 + c] = fmaxf(r, 0.0f);
    }
}

// Layer-2: gather + combined GEMM (WcT) + bc -> final output.
__global__ __launch_bounds__(256) void k_agg2(const float* __restrict__ in,
                                              const float* __restrict__ WcT,
                                              const float* __restrict__ bc,
                                              const float* __restrict__ dinv,
                                              const int* __restrict__ cur,
                                              const int2* __restrict__ eb,
                                              const int* __restrict__ ovf_cnt,
                                              const int4* __restrict__ ovf,
                                              float* __restrict__ out, int N) {
    __shared__ float Wt[64 * WPAD];
    __shared__ float rbuf[4 * 64];
    int tid = threadIdx.x;
    {
        const float4* W4 = (const float4*)WcT;   // WcT[j*64+i]: row j = out ch
        #pragma unroll
        for (int i = 0; i < 4; ++i) {
            int f4 = i * 256 + tid;
            float4 v = W4[f4];
            int j = f4 >> 4;
            int i0 = (f4 & 15) * 4;
            float4* dst = (float4*)(Wt + j * WPAD + i0);
            *dst = v;                            // row-contiguous: b128 write
        }
    }
    __syncthreads();
    int w = tid >> 6, c = tid & 63;
    float* rw = rbuf + w * 64;
    for (int it = 0; it < 4; ++it) {
        int n = blockIdx.x * 16 + it * 4 + w;
        if (n >= N) continue;
        float dv = dinv[n];
        float selfv = in[(size_t)n * 64 + c];
        float a0 = 0.f, a1 = 0.f, a2 = 0.f, a3 = 0.f;
        const int2* bkt = eb + (size_t)n * CAP;
        int mfull = cur[n];
        int m = mfull > CAP ? CAP : mfull;
        int i = 0;
        for (; i + 8 <= m; i += 8) {
            int2 e0 = bkt[i + 0], e1 = bkt[i + 1], e2 = bkt[i + 2], e3 = bkt[i + 3];
            int2 e4 = bkt[i + 4], e5 = bkt[i + 5], e6 = bkt[i + 6], e7 = bkt[i + 7];
            float d0 = dinv[e0.x], d1 = dinv[e1.x], d2 = dinv[e2.x], d3 = dinv[e3.x];
            float d4 = dinv[e4.x], d5 = dinv[e5.x], d6 = dinv[e6.x], d7 = dinv[e7.x];
            float v0 = in[(size_t)e0.x * 64 + c], v1 = in[(size_t)e1.x * 64 + c];
            float v2 = in[(size_t)e2.x * 64 + c], v3 = in[(size_t)e3.x * 64 + c];
            float v4 = in[(size_t)e4.x * 64 + c], v5 = in[(size_t)e5.x * 64 + c];
            float v6 = in[(size_t)e6.x * 64 + c], v7 = in[(size_t)e7.x * 64 + c];
            a0 = fmaf(v0, __int_as_float(e0.y) * d0, a0);
            a1 = fmaf(v1, __int_as_float(e1.y) * d1, a1);
            a2 = fmaf(v2, __int_as_float(e2.y) * d2, a2);
            a3 = fmaf(v3, __int_as_float(e3.y) * d3, a3);
            a0 = fmaf(v4, __int_as_float(e4.y) * d4, a0);
            a1 = fmaf(v5, __int_as_float(e5.y) * d5, a1);
            a2 = fmaf(v6, __int_as_float(e6.y) * d6, a2);
            a3 = fmaf(v7, __int_as_float(e7.y) * d7, a3);
        }
        for (; i < m; ++i) {
            int2 e = bkt[i];
            a0 = fmaf(in[(size_t)e.x * 64 + c], __int_as_float(e.y) * dinv[e.x], a0);
        }
        if (mfull > CAP) {
            int oc = *ovf_cnt; if (oc > OVF_MAX) oc = OVF_MAX;
            for (int k = 0; k < oc; ++k) {
                int4 o = ovf[k];
                if (o.y == n)
                    a0 = fmaf(in[(size_t)o.x * 64 + c], __int_as_float(o.z) * dinv[o.x], a0);
            }
        }
        float r = fmaf(dv, ((a0 + a1) + (a2 + a3)) + selfv * dv, 0.0f);
        // LDS-staged GEMM: out[n][c] = bc[c] + sum_i r[i] * Wc[i][c]
        rw[c] = r;
        float acc = bc[c];
        const float4* rb4 = (const float4*)rw;
        const float4* wt4 = (const float4*)(Wt + c * WPAD);
        #pragma unroll
        for (int q = 0; q < 16; ++q) {
            float4 rv = rb4[q];
            float4 wv = wt4[q];
            acc = fmaf(rv.x, wv.x, acc);
            acc = fmaf(rv.y, wv.y, acc);
            acc = fmaf(rv.z, wv.z, acc);
            acc = fmaf(rv.w, wv.w, acc);
        }
        out[(size_t)n * 64 + c] = acc;
    }
}

// ---------------- launcher ----------------

extern "C" void kernel_launch(void* const* d_in, const int* in_sizes, int n_in,
                              void* d_out, int out_size, void* d_ws, size_t ws_size,
                              hipStream_t stream) {
    const float* x    = (const float*)d_in[0];
    const int*   ei   = (const int*)d_in[1];
    const float* ea   = (const float*)d_in[2];
    const float* W1   = (const float*)d_in[3];
    const float* b1   = (const float*)d_in[4];
    const float* W2   = (const float*)d_in[5];
    const float* b2   = (const float*)d_in[6];
    const float* Wout = (const float*)d_in[7];
    const float* bout = (const float*)d_in[8];
    float* out = (float*)d_out;

    const int N = in_sizes[0] / (64 * 16);   // 50000
    const int E = in_sizes[1] / 2;           // 800000

    // workspace layout
    char* wsb = (char*)d_ws;
    int4*  ovf  = (int4*)wsb;                       // 128KB
    int2*  eb   = (int2*)(wsb + OVF_MAX * 16);      // N*CAP*8B
    float* H1   = (float*)(wsb + OVF_MAX * 16 + (size_t)N * CAP * 8);
    size_t NC = (size_t)N * 64;
    float* Z    = H1 + NC;
    int*   cur  = (int*)(Z + NC);
    float* dinv = (float*)(cur + N);
    int*   ovfc = (int*)(dinv + N);
    float* WcT  = (float*)(ovfc + 4);
    float* bc   = WcT + 4096;

    dim3 b256(256);
    int meanBlocks    = (N + 15) / 16;       // 3125
    int scatterBlocks = (E + 255) / 256;     // 3125
    int zb = (N + 256) / 256;                // covers n == N too

    hipLaunchKernelGGL(k_pre, dim3(zb + 17), b256, 0, stream,
                       cur, ovfc, N, W2, Wout, b2, bout, WcT, bc, zb);
    hipLaunchKernelGGL(k_scatmean, dim3(scatterBlocks + meanBlocks), b256, 0, stream,
                       ei, ea, cur, eb, ovfc, ovf, E, scatterBlocks, x, W1, H1, N);
    hipLaunchKernelGGL(k_dinvb, dim3((N + 63) / 64), b256, 0, stream,
                       cur, eb, ovfc, ovf, dinv, N);
    hipLaunchKernelGGL(k_agg1, dim3(meanBlocks), b256, 0, stream,
                       H1, b1, dinv, cur, eb, ovfc, ovf, Z, N);
    hipLaunchKernelGGL(k_agg2, dim3(meanBlocks), b256, 0, stream,
                       Z, WcT, bc, dinv, cur, eb, ovfc, ovf, out, N);
}